// Round 1
// baseline (1973.629 us; speedup 1.0000x reference)
//
#include <hip/hip_runtime.h>
#include <hip/hip_bf16.h>

#define NTOK 98
#define DIM 192
#define HEADS 6
#define HD 32
#define SCALE 0.17677669529663687f

// ---------------- kernel 0: bias[h][i][j] = rpb_table[rel_idx[i][j]][h] ----------------
__global__ void bias_kernel(const float* __restrict__ rpb, const int* __restrict__ rel_idx,
                            float* __restrict__ biasF) {
    int e = blockIdx.x * 256 + threadIdx.x;
    if (e >= HEADS * NTOK * NTOK) return;
    int h  = e / (NTOK * NTOK);
    int ij = e % (NTOK * NTOK);
    biasF[e] = rpb[rel_idx[ij] * HEADS + h];
}

// ---------------- kernel 1: fused kv-GEMM + attention, writes o (pre-proj) to d_out ----
#define T1 512
__launch_bounds__(T1, 1)
__global__ void attn_kernel(const float* __restrict__ skip, const float* __restrict__ x_up,
                            const float* __restrict__ mask, const float* __restrict__ kv_w,
                            const float* __restrict__ kv_b, const float* __restrict__ biasF,
                            float* __restrict__ o_out) {
    __shared__ __hip_bfloat16 kv_s[2 * NTOK * DIM];   // k then v, bf16: 75264 B
    __shared__ float S[NTOK * 101];                   // scores (also reused as bf16 skip): 39592 B
    __shared__ float qs[NTOK * 33];                   // q staging, padded: 12936 B

    const int b   = blockIdx.x;
    const int tid = threadIdx.x;

    // --- Phase A0: skip -> LDS (bf16), overlaying the S region ---
    __hip_bfloat16* sk = (__hip_bfloat16*)S;          // 37632 B <= 39592 B
    const float* skp = skip + (size_t)b * NTOK * DIM;
    for (int e = tid; e < NTOK * DIM; e += T1) sk[e] = __float2bfloat16(skp[e]);
    __syncthreads();

    // --- Phase A1: kv = skip @ kv_w + kv_b ; cols [0,192)=k, [192,384)=v ---
    for (int g = tid; g < NTOK * 96; g += T1) {
        int i  = g / 96;
        int c4 = (g % 96) * 4;
        float4 acc = *(const float4*)(kv_b + c4);
        const __hip_bfloat16* skr = sk + i * DIM;
        const float* wp = kv_w + c4;
        #pragma unroll 4
        for (int d = 0; d < DIM; ++d) {
            float a = __bfloat162float(skr[d]);
            float4 w = *(const float4*)(wp + (size_t)d * 384);
            acc.x += a * w.x; acc.y += a * w.y; acc.z += a * w.z; acc.w += a * w.w;
        }
        __hip_bfloat16* dst = kv_s + ((c4 < DIM) ? (i * DIM + c4)
                                                 : (NTOK * DIM + i * DIM + (c4 - DIM)));
        dst[0] = __float2bfloat16(acc.x);
        dst[1] = __float2bfloat16(acc.y);
        dst[2] = __float2bfloat16(acc.z);
        dst[3] = __float2bfloat16(acc.w);
    }
    __syncthreads();   // sk (== S region) no longer needed; kv_s ready

    const float* mw = mask + (size_t)(b & 63) * NTOK * NTOK;
    float* ob = o_out + (size_t)b * NTOK * DIM;

    for (int h = 0; h < HEADS; ++h) {
        // --- stage q (scaled) and prefill S with bias+mask (coalesced) ---
        const float* xq = x_up + (size_t)b * NTOK * DIM + h * HD;
        for (int e = tid; e < NTOK * HD; e += T1) {
            int i = e >> 5, d = e & 31;
            qs[i * 33 + d] = xq[i * DIM + d] * SCALE;
        }
        const float* bh = biasF + h * NTOK * NTOK;
        for (int e = tid; e < NTOK * NTOK; e += T1) {
            int i = e / NTOK, j = e % NTOK;
            S[i * 101 + j] = bh[e] + mw[e];
        }
        __syncthreads();

        // --- S += q . k  (lanes vary i -> qs stride-33 2-way free; k broadcast) ---
        for (int e = tid; e < NTOK * NTOK; e += T1) {
            int i = e % NTOK, j = e / NTOK;
            const float* qr = qs + i * 33;
            const __hip_bfloat16* kr = kv_s + j * DIM + h * HD;
            float acc = 0.f;
            #pragma unroll 8
            for (int d = 0; d < HD; ++d) acc += qr[d] * __bfloat162float(kr[d]);
            S[i * 101 + j] += acc;
        }
        __syncthreads();

        // --- softmax, one thread per row ---
        for (int r = tid; r < NTOK; r += T1) {
            float* Sr = S + r * 101;
            float m = -1e30f;
            for (int j = 0; j < NTOK; ++j) m = fmaxf(m, Sr[j]);
            float s = 0.f;
            for (int j = 0; j < NTOK; ++j) { float ev = __expf(Sr[j] - m); Sr[j] = ev; s += ev; }
            float inv = 1.0f / s;
            for (int j = 0; j < NTOK; ++j) Sr[j] *= inv;
        }
        __syncthreads();

        // --- O = P @ v ; write fp32 o into d_out (pre-proj) ---
        for (int e = tid; e < NTOK * HD; e += T1) {
            int i = e >> 5, d = e & 31;
            const float* Pr = S + i * 101;
            const __hip_bfloat16* vr = kv_s + NTOK * DIM + h * HD + d;
            float acc = 0.f;
            #pragma unroll 7
            for (int j = 0; j < NTOK; ++j) acc += Pr[j] * __bfloat162float(vr[j * DIM]);
            ob[i * DIM + h * HD + d] = acc;
        }
        __syncthreads();   // protect S/qs rewrite next head
    }
}

// ---------------- kernel 2: in-place proj GEMM over d_out ----------------
#define T2 256
__launch_bounds__(T2)
__global__ void proj_kernel(float* __restrict__ io, const float* __restrict__ pw,
                            const float* __restrict__ pb) {
    __shared__ __hip_bfloat16 os[NTOK * DIM];   // 37632 B
    const int b = blockIdx.x, tid = threadIdx.x;
    float* rowp = io + (size_t)b * NTOK * DIM;
    for (int e = tid; e < NTOK * DIM; e += T2) os[e] = __float2bfloat16(rowp[e]);
    __syncthreads();
    for (int g = tid; g < NTOK * 48; g += T2) {
        int r  = g / 48;
        int m4 = (g % 48) * 4;
        float4 acc = *(const float4*)(pb + m4);
        const __hip_bfloat16* orow = os + r * DIM;
        const float* wp = pw + m4;
        #pragma unroll 4
        for (int c = 0; c < DIM; ++c) {
            float a = __bfloat162float(orow[c]);
            float4 w = *(const float4*)(wp + (size_t)c * DIM);
            acc.x += a * w.x; acc.y += a * w.y; acc.z += a * w.z; acc.w += a * w.w;
        }
        *(float4*)(rowp + r * DIM + m4) = acc;
    }
}

extern "C" void kernel_launch(void* const* d_in, const int* in_sizes, int n_in,
                              void* d_out, int out_size, void* d_ws, size_t ws_size,
                              hipStream_t stream) {
    const float* skip   = (const float*)d_in[0];
    const float* x_up   = (const float*)d_in[1];
    const float* mask   = (const float*)d_in[2];
    const float* kv_w   = (const float*)d_in[3];
    const float* kv_b   = (const float*)d_in[4];
    const float* proj_w = (const float*)d_in[5];
    const float* proj_b = (const float*)d_in[6];
    const float* rpb    = (const float*)d_in[7];
    const int*   relidx = (const int*)d_in[8];
    float* out = (float*)d_out;

    float* biasF = (float*)d_ws;   // 6*98*98*4 = 230496 B

    int bias_elems = HEADS * NTOK * NTOK;
    bias_kernel<<<(bias_elems + 255) / 256, 256, 0, stream>>>(rpb, relidx, biasF);
    attn_kernel<<<1024, T1, 0, stream>>>(skip, x_up, mask, kv_w, kv_b, biasF, out);
    proj_kernel<<<1024, T2, 0, stream>>>(out, proj_w, proj_b);
}

// Round 2
// 336.403 us; speedup vs baseline: 5.8669x; 5.8669x over previous
//
#include <hip/hip_runtime.h>
#include <hip/hip_bf16.h>

#define NTOK 98
#define DIM 192
#define HEADS 6
#define SCALE 0.17677669529663687f

using shortx8 = __attribute__((ext_vector_type(8))) short;
using floatx4 = __attribute__((ext_vector_type(4))) float;

static __device__ __forceinline__ unsigned short f2bf(float f) {
    unsigned u = __float_as_uint(f);
    u += 0x7FFFu + ((u >> 16) & 1u);   // RNE
    return (unsigned short)(u >> 16);
}

static __device__ __forceinline__ shortx8 pack8(const float* p, float scale) {
    float4 a = *(const float4*)p;
    float4 b = *(const float4*)(p + 4);
    shortx8 t;
    t[0] = (short)f2bf(a.x * scale); t[1] = (short)f2bf(a.y * scale);
    t[2] = (short)f2bf(a.z * scale); t[3] = (short)f2bf(a.w * scale);
    t[4] = (short)f2bf(b.x * scale); t[5] = (short)f2bf(b.y * scale);
    t[6] = (short)f2bf(b.z * scale); t[7] = (short)f2bf(b.w * scale);
    return t;
}

// ---------------- prep: bias gather + weight bf16 fragment-linear layouts ----------------
// kvB[((ks*24+NT)*64+lane)*8+jj] = kv_w[(ks*32+quad*8+jj)*384 + NT*16+(lane&15)]
// pB [((ks*12+NT)*64+lane)*8+jj] = proj_w[(ks*32+quad*8+jj)*192 + NT*16+(lane&15)]
__global__ void prep_kernel(const float* __restrict__ rpb, const int* __restrict__ relidx,
                            const float* __restrict__ kvw, const float* __restrict__ pw,
                            float* __restrict__ biasF, unsigned short* __restrict__ kvB,
                            unsigned short* __restrict__ pB) {
    int e = blockIdx.x * 256 + threadIdx.x;
    if (e < HEADS * NTOK * NTOK) {
        int h = e / (NTOK * NTOK), ij = e % (NTOK * NTOK);
        biasF[e] = rpb[relidx[ij] * HEADS + h];
    }
    if (e < 73728) {
        int jj = e & 7, lane = (e >> 3) & 63, t = e >> 9;
        int NT = t % 24, ks = t / 24;
        int c = ks * 32 + (lane >> 4) * 8 + jj;
        int n = NT * 16 + (lane & 15);
        kvB[e] = f2bf(kvw[c * 384 + n]);
    }
    if (e < 36864) {
        int jj = e & 7, lane = (e >> 3) & 63, t = e >> 9;
        int NT = t % 12, ks = t / 12;
        int c = ks * 32 + (lane >> 4) * 8 + jj;
        int n = NT * 16 + (lane & 15);
        pB[e] = f2bf(pw[c * 192 + n]);
    }
}

// ---------------- attn: kv-GEMM + QK + softmax + PV (MFMA), per (window, 3-head group) ----
__global__ __launch_bounds__(448, 4) void attn_kernel(
    const float* __restrict__ skip, const float* __restrict__ xup,
    const float* __restrict__ mask, const float* __restrict__ kv_b,
    const float* __restrict__ biasF, const unsigned short* __restrict__ kvB,
    float* __restrict__ o_out) {

    // fragment-linear LDS: lane-consecutive 16B -> conflict-free ds_read_b128
    __shared__ unsigned short kB3[3 * 7 * 512];      // [h'][tj][lane][8]  k[j][dh]
    __shared__ unsigned short vB3[3 * 2 * 4 * 512];  // [h'][nt][ks][lane][8]  v[j][dh]
    __shared__ unsigned short PA[7 * 4 * 512];       // [mt][ks][lane][8]  P[m][j]

    const int tid  = threadIdx.x;
    const int w    = tid >> 6;        // wave id = mtile
    const int lane = tid & 63;
    const int l15  = lane & 15;
    const int quad = lane >> 4;
    const int win  = blockIdx.x >> 1;
    const int g    = blockIdx.x & 1;  // head group: heads 3g..3g+2

    // zero pad slabs (v tokens 98..127; P cols 112..127)
    for (int e = tid; e < 6 * 512; e += 448)
        vB3[(e / 512) * 4 * 512 + 3 * 512 + (e & 511)] = 0;
    for (int e = tid; e < 7 * 256; e += 448)
        PA[(e / 256) * 4 * 512 + 3 * 512 + 256 + (e & 255)] = 0;
    __syncthreads();

    const int mA  = w * 16 + l15;          // A-frag row (token)
    const int mAc = mA < NTOK ? mA : 97;   // clamp pad rows (finite, discarded later)

    // ---- phase 1: kv slice GEMM (cols for this head group), M=112 K=192 N=192 ----
    shortx8 afr[6];
    {
        const float* sr = skip + ((size_t)win * NTOK + mAc) * DIM + quad * 8;
        #pragma unroll
        for (int ks = 0; ks < 6; ++ks) afr[ks] = pack8(sr + ks * 32, 1.0f);
    }
    #pragma unroll
    for (int nt = 0; nt < 12; ++nt) {
        const int NTg = (nt < 6) ? (6 * g + nt) : (6 + 6 * g + nt);  // global kv_w col tile
        const int col = NTg * 16 + l15;
        const float cb = kv_b[col];
        floatx4 acc = {cb, cb, cb, cb};
        #pragma unroll
        for (int ks = 0; ks < 6; ++ks) {
            shortx8 bf = *(const shortx8*)(kvB + ((size_t)((ks * 24 + NTg) * 64 + lane)) * 8);
            acc = __builtin_amdgcn_mfma_f32_16x16x32_bf16(afr[ks], bf, acc, 0, 0, 0);
        }
        if (nt < 6) {  // k part -> kB3 (B-frag layout for QK: k[j][dh])
            const int ch = nt * 16 + l15, hh = ch >> 5, dh = ch & 31;
            const int base = ((hh * 7 + w) * 64) * 8 + (dh & 7);
            const int lphi = ((dh >> 3) & 3) << 4;
            #pragma unroll
            for (int r = 0; r < 4; ++r) {
                int mm = quad * 4 + r;  // m&15 (write pad rows too: finite row-97 copies)
                kB3[base + (mm | lphi) * 8] = f2bf(acc[r]);
            }
        } else {       // v part -> vB3 (B-frag layout for PV: v[j][dh], token on K axis)
            const int cv = (nt - 6) * 16 + l15, hh = cv >> 5, dh = cv & 31, ntv = dh >> 4;
            #pragma unroll
            for (int r = 0; r < 4; ++r) {
                int m = w * 16 + quad * 4 + r;
                if (m < NTOK) {
                    int lp = (dh & 15) | (((m >> 3) & 3) << 4);
                    vB3[(((hh * 2 + ntv) * 4 + (m >> 5)) * 64 + lp) * 8 + (m & 7)] = f2bf(acc[r]);
                }
            }
        }
    }
    __syncthreads();

    const float* mw = mask + (size_t)(win & 63) * NTOK * NTOK;

    for (int hp = 0; hp < 3; ++hp) {
        const int h = 3 * g + hp;
        // q A-frag (scaled) direct from global
        shortx8 qf;
        {
            const float* xr = xup + ((size_t)win * NTOK + mAc) * DIM + h * 32 + quad * 8;
            qf = pack8(xr, SCALE);
        }
        // C-init: bias + mask (pad cols -> -1e30 so softmax -> exact 0)
        floatx4 S[7];
        const float* bh = biasF + h * NTOK * NTOK;
        #pragma unroll
        for (int nt = 0; nt < 7; ++nt) {
            const int j = nt * 16 + l15;
            #pragma unroll
            for (int r = 0; r < 4; ++r) {
                int i = w * 16 + quad * 4 + r;
                int ic = i < NTOK ? i : 97;
                S[nt][r] = (j < NTOK) ? (bh[ic * NTOK + j] + mw[ic * NTOK + j]) : -1e30f;
            }
        }
        // QK: S += q . k^T  (K=32, one MFMA per n-tile)
        #pragma unroll
        for (int nt = 0; nt < 7; ++nt) {
            shortx8 bk = *(const shortx8*)&kB3[((hp * 7 + nt) * 64 + lane) * 8];
            S[nt] = __builtin_amdgcn_mfma_f32_16x16x32_bf16(qf, bk, S[nt], 0, 0, 0);
        }
        // softmax fully in registers (row = 16 lanes of this quad, 7 tiles)
        float inv[4];
        #pragma unroll
        for (int r = 0; r < 4; ++r) {
            float mx = S[0][r];
            #pragma unroll
            for (int nt = 1; nt < 7; ++nt) mx = fmaxf(mx, S[nt][r]);
            mx = fmaxf(mx, __shfl_xor(mx, 1));
            mx = fmaxf(mx, __shfl_xor(mx, 2));
            mx = fmaxf(mx, __shfl_xor(mx, 4));
            mx = fmaxf(mx, __shfl_xor(mx, 8));
            float sm = 0.f;
            #pragma unroll
            for (int nt = 0; nt < 7; ++nt) { float ev = __expf(S[nt][r] - mx); S[nt][r] = ev; sm += ev; }
            sm += __shfl_xor(sm, 1);
            sm += __shfl_xor(sm, 2);
            sm += __shfl_xor(sm, 4);
            sm += __shfl_xor(sm, 8);
            inv[r] = 1.0f / sm;
        }
        // P -> LDS in A-frag layout
        #pragma unroll
        for (int nt = 0; nt < 7; ++nt) {
            const int j = nt * 16 + l15;
            const int ks = nt >> 1;
            const int lphi = ((j >> 3) & 3) << 4;
            #pragma unroll
            for (int r = 0; r < 4; ++r) {
                int mm = quad * 4 + r;
                PA[((w * 4 + ks) * 64 + (mm | lphi)) * 8 + (j & 7)] = f2bf(S[nt][r] * inv[r]);
            }
        }
        __syncthreads();
        // PV: O[m][dh] = P @ v, K=128 (4 ksteps), N=32 (2 ntiles)
        shortx8 pa[4];
        #pragma unroll
        for (int ks = 0; ks < 4; ++ks)
            pa[ks] = *(const shortx8*)&PA[((w * 4 + ks) * 64 + lane) * 8];
        #pragma unroll
        for (int nt = 0; nt < 2; ++nt) {
            floatx4 o = {0.f, 0.f, 0.f, 0.f};
            #pragma unroll
            for (int ks = 0; ks < 4; ++ks) {
                shortx8 vb = *(const shortx8*)&vB3[(((hp * 2 + nt) * 4 + ks) * 64 + lane) * 8];
                o = __builtin_amdgcn_mfma_f32_16x16x32_bf16(pa[ks], vb, o, 0, 0, 0);
            }
            #pragma unroll
            for (int r = 0; r < 4; ++r) {
                int m = w * 16 + quad * 4 + r;
                if (m < NTOK)
                    o_out[((size_t)win * NTOK + m) * DIM + h * 32 + nt * 16 + l15] = o[r];
            }
        }
        __syncthreads();  // PA reused next head
    }
}

// ---------------- proj: out = O @ proj_w + proj_b, in-place on d_out (MFMA) ----------------
__global__ __launch_bounds__(448, 4) void proj_kernel(
    float* __restrict__ io, const unsigned short* __restrict__ pB,
    const float* __restrict__ pb) {
    const int tid  = threadIdx.x;
    const int w    = tid >> 6;
    const int lane = tid & 63;
    const int l15  = lane & 15;
    const int quad = lane >> 4;
    const int win  = blockIdx.x;

    float* base = io + (size_t)win * NTOK * DIM;
    const int mA  = w * 16 + l15;
    const int mAc = mA < NTOK ? mA : 97;

    // A-frags: this wave's own 16 rows (all K) -> regs BEFORE any store (in-place safe:
    // each wave reads & writes only its own mtile's rows)
    shortx8 afr[6];
    {
        const float* ar = base + mAc * DIM + quad * 8;
        #pragma unroll
        for (int ks = 0; ks < 6; ++ks) afr[ks] = pack8(ar + ks * 32, 1.0f);
    }
    #pragma unroll
    for (int nt = 0; nt < 12; ++nt) {
        const int n = nt * 16 + l15;
        const float bb = pb[n];
        floatx4 acc = {bb, bb, bb, bb};
        #pragma unroll
        for (int ks = 0; ks < 6; ++ks) {
            shortx8 bf = *(const shortx8*)(pB + ((size_t)((ks * 12 + nt) * 64 + lane)) * 8);
            acc = __builtin_amdgcn_mfma_f32_16x16x32_bf16(afr[ks], bf, acc, 0, 0, 0);
        }
        #pragma unroll
        for (int r = 0; r < 4; ++r) {
            int m = w * 16 + quad * 4 + r;
            if (m < NTOK) base[m * DIM + n] = acc[r];
        }
    }
}

extern "C" void kernel_launch(void* const* d_in, const int* in_sizes, int n_in,
                              void* d_out, int out_size, void* d_ws, size_t ws_size,
                              hipStream_t stream) {
    const float* skip   = (const float*)d_in[0];
    const float* x_up   = (const float*)d_in[1];
    const float* mask   = (const float*)d_in[2];
    const float* kv_w   = (const float*)d_in[3];
    const float* kv_b   = (const float*)d_in[4];
    const float* proj_w = (const float*)d_in[5];
    const float* proj_b = (const float*)d_in[6];
    const float* rpb    = (const float*)d_in[7];
    const int*   relidx = (const int*)d_in[8];
    float* out = (float*)d_out;

    float*          biasF = (float*)d_ws;                               // 230496 B
    unsigned short* kvB   = (unsigned short*)((char*)d_ws + 230496);    // 147456 B
    unsigned short* pB    = (unsigned short*)((char*)d_ws + 377952);    //  73728 B

    prep_kernel<<<288, 256, 0, stream>>>(rpb, relidx, kv_w, proj_w, biasF, kvB, pB);
    attn_kernel<<<2048, 448, 0, stream>>>(skip, x_up, mask, kv_b, biasF, kvB, out);
    proj_kernel<<<1024, 448, 0, stream>>>(out, pB, proj_b);
}